// Round 4
// baseline (227616.553 us; speedup 1.0000x reference)
//
#include <hip/hip_runtime.h>
#include <stdint.h>
#include <stddef.h>

// MemoryUnit recurrent scan on MI355X (gfx950), round 4.
// 32 blocks x 512 threads; each block owns TWO batch elements (waves 0-3 ->
// batch 0, waves 4-7 -> batch 1) so both wave-groups reuse the same weight
// fragments each step (halves HBM weight streaming). GEMM1 is phase-split
// (k|v before attention, eg|wc after r) so one [16][520] f32 buffer per batch
// serves both. x-projections are precomputed into d_ws by a pre-pass GEMM
// (xproj_kernel) when scratch is large enough; otherwise computed in-loop per
// 4-step window. All GEMMs bf16x3 (hi/lo split), fp32 master state, exact
// erf-GELU -- precision identical to the passing round-3 kernel.

#define SLEN 2048
#define NB   64
#define DD   256
#define TPB  512
#define KVS  520      // kv/egwc row stride in floats

typedef __attribute__((ext_vector_type(8))) short v8bf;
typedef __attribute__((ext_vector_type(4))) float v4f;

__device__ __forceinline__ float bf2f(uint16_t h){
  union { uint32_t u; float f; } v; v.u = ((uint32_t)h) << 16; return v.f;
}
__device__ __forceinline__ uint16_t f2bf(float f){
  union { float f; uint32_t u; } v; v.f = f;
  uint32_t u = v.u;
  return (uint16_t)((u + 0x7FFFu + ((u >> 16) & 1u)) >> 16);
}
__device__ __forceinline__ void splitf(float f, uint16_t& h, uint16_t& l){
  h = f2bf(f);
  l = f2bf(f - bf2f(h));
}
__device__ __forceinline__ float geluf(float xx){
  return 0.5f * xx * (1.0f + erff(xx * 0.70710678118654752f));
}
__device__ __forceinline__ float sigmf(float xx){
  return 1.0f / (1.0f + expf(-xx));
}
__device__ __forceinline__ v4f MFMA16(v8bf a, v8bf b, v4f c){
  return __builtin_amdgcn_mfma_f32_16x16x32_bf16(a, b, c, 0, 0, 0);
}

// A-fragment load+split from fp32 LDS tile [R][256], row-swizzled:
// element (row,k) at byte row*1024 + ((k*4) ^ ((row&7)<<5)).
template<int RM>
__device__ __forceinline__ void ldA_f32(const char* base, int lane, int kc,
                                        v8bf& hi, v8bf& lo){
  int row = lane & RM;
  int off = row * 1024 + (((kc << 7) + ((lane >> 4) << 5)) ^ ((row & 7) << 5));
  const float* p = (const float*)(base + off);
  union { v8bf v; uint16_t u[8]; } H, L;
  #pragma unroll
  for (int j = 0; j < 8; ++j) splitf(p[j], H.u[j], L.u[j]);
  hi = H.v; lo = L.v;
}

// ---------------- weight packing ----------------
// B-fragment layout for mfma_f32_16x16x32_bf16: lane l holds col n=nt*16+(l&15),
// k = kc*32 + (l>>4)*8 + j. Packed [nt][kc][lane][8]. hi=bf16(w), lo=bf16(w-hi).
__global__ __launch_bounds__(256) void prep_kernel(
    const float* __restrict__ Wq, const float* __restrict__ Wk, const float* __restrict__ Wv,
    const float* __restrict__ wg1W, const float* __restrict__ egW, const float* __restrict__ wcW,
    const float* __restrict__ fuW,
    const float* __restrict__ bq, const float* __restrict__ bwg1, const float* __restrict__ beg,
    const float* __restrict__ bwc, const float* __restrict__ bfu,
    const float* __restrict__ bk, const float* __restrict__ bv,
    uint16_t* __restrict__ wbigh, uint16_t* __restrict__ wbigl,
    uint16_t* __restrict__ wrfh,
    uint16_t* __restrict__ wxfh, uint16_t* __restrict__ wxfl,
    float* __restrict__ bxall, float* __restrict__ bkv)
{
  int idx = blockIdx.x * 256 + threadIdx.x;
  if (idx < 262144){                               // Wbig: [Wk|Wv|egM|wcM] 256x1024
    int j = idx & 7, lane = (idx >> 3) & 63, kc = (idx >> 9) & 7, nt = idx >> 12;
    int k = kc*32 + ((lane >> 4) << 3) + j;
    int n = nt*16 + (lane & 15);
    float v;
    if (n < 256)      v = Wk[k*256 + n];
    else if (n < 512) v = Wv[k*256 + n - 256];
    else if (n < 768) v = egW[(256 + k)*256 + n - 512];
    else              v = wcW[(256 + k)*256 + n - 768];
    uint16_t h, l; splitf(v, h, l);
    wbigh[idx] = h; wbigl[idx] = l;
  }
  int i2 = idx - 262144;
  if (i2 >= 0 && i2 < 131072){                     // Wr: [wg1_r|fu_r] 256x512 (hi only)
    int j = i2 & 7, lane = (i2 >> 3) & 63, kc = (i2 >> 9) & 7, nt = i2 >> 12;
    int k = kc*32 + ((lane >> 4) << 3) + j;
    int n = nt*16 + (lane & 15);
    float v = (n < 256) ? wg1W[(256 + k)*256 + n] : fuW[(256 + k)*256 + n - 256];
    wrfh[i2] = f2bf(v);
  }
  int i3 = idx - 393216;
  if (i3 >= 0 && i3 < 327680){                     // Wx: [Wq|wg1_x|eg_x|wc_x|fu_x] 256x1280
    int j = i3 & 7, lane = (i3 >> 3) & 63, kc = (i3 >> 9) & 7, nt = i3 >> 12;
    int k = kc*32 + ((lane >> 4) << 3) + j;
    int n = nt*16 + (lane & 15);
    float v;
    if (n < 256)       v = Wq[k*256 + n];
    else if (n < 512)  v = wg1W[k*256 + n - 256];
    else if (n < 768)  v = egW[k*256 + n - 512];
    else if (n < 1024) v = wcW[k*256 + n - 768];
    else               v = fuW[k*256 + n - 1024];
    uint16_t h, l; splitf(v, h, l);
    wxfh[i3] = h; wxfl[i3] = l;
  }
  int i4 = idx - 720896;
  if (i4 >= 0 && i4 < 1280){
    float v;
    if (i4 < 256)       v = bq[i4];
    else if (i4 < 512)  v = bwg1[i4 - 256];
    else if (i4 < 768)  v = beg[i4 - 512];
    else if (i4 < 1024) v = bwc[i4 - 768];
    else                v = bfu[i4 - 1024];
    bxall[i4] = v;
  }
  int i5 = idx - 722176;
  if (i5 >= 0 && i5 < 512){
    bkv[i5] = (i5 < 256) ? bk[i5] : bv[i5 - 256];
  }
}

// ---------------- x-projection pre-pass ----------------
// Xpg[row][1280] = x_flat[row][0:256] @ Wx + bx, rows = t*64+b (natural flat).
__global__ __launch_bounds__(256) void xproj_kernel(
    const float* __restrict__ x,
    const uint16_t* __restrict__ wxfh, const uint16_t* __restrict__ wxfl,
    const float* __restrict__ bxall, float* __restrict__ Xpg)
{
  __shared__ char xs[16384];                       // [16][256] f32 swizzled
  const int tid = threadIdx.x;
  const int lane = tid & 63;
  const int wv = tid >> 6;
  const int r0 = blockIdx.x * 16;
  {
    int row = tid >> 4;
    int c0 = (tid & 15) * 16;
    const float* xp = x + (size_t)(r0 + row) * 256 + c0;
    #pragma unroll
    for (int q = 0; q < 4; ++q){
      v4f v = *(const v4f*)(xp + q*4);
      int c = c0 + q*4;
      *(v4f*)(xs + row*1024 + ((c*4) ^ ((row & 7) << 5))) = v;
    }
  }
  __syncthreads();
  v8bf ah[8], al[8];
  #pragma unroll
  for (int kc = 0; kc < 8; ++kc) ldA_f32<15>(xs, lane, kc, ah[kc], al[kc]);
  for (int i = 0; i < 20; ++i){
    int nt = wv * 20 + i;
    const v8bf* bph = ((const v8bf*)wxfh) + (nt*8)*64 + lane;
    const v8bf* bpl = ((const v8bf*)wxfl) + (nt*8)*64 + lane;
    v8bf bh[8], bl[8];
    #pragma unroll
    for (int kc = 0; kc < 8; ++kc){ bh[kc] = bph[kc*64]; bl[kc] = bpl[kc*64]; }
    v4f acc = {0.f, 0.f, 0.f, 0.f};
    #pragma unroll
    for (int kc = 0; kc < 8; ++kc) acc = MFMA16(ah[kc], bh[kc], acc);
    #pragma unroll
    for (int kc = 0; kc < 8; ++kc) acc = MFMA16(ah[kc], bl[kc], acc);
    #pragma unroll
    for (int kc = 0; kc < 8; ++kc) acc = MFMA16(al[kc], bh[kc], acc);
    int n = nt*16 + (lane & 15);
    int rr = (lane >> 4) * 4;
    float bias = bxall[n];
    #pragma unroll
    for (int r = 0; r < 4; ++r)
      Xpg[(size_t)(r0 + rr + r) * 1280 + n] = acc[r] + bias;
  }
}

// ---------------- main persistent kernel ----------------
// LDS (bytes): MfB 0..32768 (2x[16][256]f32 swz) | xbB 32768..40960
// (2x[4][256]f32 swz) | XpL 40960..81920 (2x[4][1280]f32) | kvb 81920..148480
// (2x[16][520]f32) | rb 148480..150528 | mv 150528..154624 | sc 154624..155648
#define SM_BYTES 155648

__global__ __launch_bounds__(TPB, 2) void memunit_kernel(
    const float* __restrict__ x, const float* __restrict__ slot_init,
    const float* __restrict__ wg2W, const float* __restrict__ wg2b,
    const float* __restrict__ wcg, const float* __restrict__ wcb,
    const float* __restrict__ fug, const float* __restrict__ fub,
    const float* __restrict__ ong, const float* __restrict__ onb,
    const uint16_t* __restrict__ wbigh, const uint16_t* __restrict__ wbigl,
    const uint16_t* __restrict__ wrfh,
    const uint16_t* __restrict__ wxfh, const uint16_t* __restrict__ wxfl,
    const float* __restrict__ bxall, const float* __restrict__ bkv,
    const float* __restrict__ Xpg, int use_pre,
    float* __restrict__ out)
{
  extern __shared__ char smem[];
  const int tid  = threadIdx.x;
  const int lane = tid & 63;
  const int wave = tid >> 6;
  const int bi   = tid >> 8;         // batch slot within block (0/1)
  const int bt   = tid & 255;        // per-batch thread id
  const int gwv  = wave & 3;         // wave index within batch group
  const int gb   = blockIdx.x * 2 + bi;  // global batch index

  char*  MfB = smem + bi*16384;
  char*  xbB = smem + 32768 + bi*4096;
  float* xp  = (float*)(smem + 40960) + bi*(4*1280);
  float* kv  = (float*)(smem + 81920) + bi*(16*KVS);
  char*  rbB = smem + 148480 + bi*1024;
  float* rb  = (float*)rbB;
  float* mvB = (float*)(smem + 150528) + bi*512;
  float* scB = (float*)(smem + 154624) + bi*128;
  // scB: [0..15] logits [16..31] pers [32..47] evict [48..51] gate partials
  //      [52..59] fu sum/sq [60..67] y sum/sq

  const float wg2b0 = wg2b[0];

  auto mfp = [&](int s, int n) -> float* {
    return (float*)(MfB + s*1024 + ((n*4) ^ ((s & 7) << 5)));
  };

  // ---- init
  {
    int s = bt >> 4;
    int c0 = (bt & 15) * 16;
    #pragma unroll
    for (int jj = 0; jj < 16; ++jj)
      *mfp(s, c0 + jj) = slot_init[s*256 + c0 + jj];
    rb[bt & 255 & 0xFF] = 0.0f;      // bt in 0..255
    rb[bt] = 0.0f;
    if (bt < 68) scB[bt] = 0.0f;
  }
  __syncthreads();

  for (int t = 0; t < SLEN; ++t){
    const int tt = t & 3;

    // ---- window start: obtain Xp rows t..t+3 and stage x chunk
    if (tt == 0){
      {
        // stage x: 4 rows x 256 f32 per batch, swizzled
        int row = bt >> 6;
        int c0 = (bt & 63) * 4;
        v4f xv4 = *(const v4f*)(x + ((size_t)(t + row) * NB + gb) * DD + c0);
        *(v4f*)(xbB + row*1024 + ((c0*4) ^ (row << 5))) = xv4;
      }
      if (use_pre){
        #pragma unroll
        for (int w = 0; w < 4; ++w){
          const float* src = Xpg + ((size_t)(t + w) * NB + gb) * 1280;
          #pragma unroll
          for (int kq = 0; kq < 5; ++kq)
            xp[w*1280 + bt + kq*256] = src[bt + kq*256];
        }
      } else {
        __syncthreads();
        v8bf ah[8], al[8];
        #pragma unroll
        for (int kc = 0; kc < 8; ++kc) ldA_f32<3>(xbB, lane, kc, ah[kc], al[kc]);
        for (int i = 0; i < 20; ++i){
          int nt = gwv * 20 + i;
          const v8bf* bph = ((const v8bf*)wxfh) + (nt*8)*64 + lane;
          const v8bf* bpl = ((const v8bf*)wxfl) + (nt*8)*64 + lane;
          v8bf bh[8], bl[8];
          #pragma unroll
          for (int kc = 0; kc < 8; ++kc){ bh[kc] = bph[kc*64]; bl[kc] = bpl[kc*64]; }
          v4f acc = {0.f, 0.f, 0.f, 0.f};
          #pragma unroll
          for (int kc = 0; kc < 8; ++kc) acc = MFMA16(ah[kc], bh[kc], acc);
          #pragma unroll
          for (int kc = 0; kc < 8; ++kc) acc = MFMA16(ah[kc], bl[kc], acc);
          #pragma unroll
          for (int kc = 0; kc < 8; ++kc) acc = MFMA16(al[kc], bh[kc], acc);
          if ((lane >> 4) == 0){
            int n = nt*16 + (lane & 15);
            float bias = bxall[n];
            #pragma unroll
            for (int r = 0; r < 4; ++r) xp[r*1280 + n] = acc[r] + bias;
          }
        }
      }
    }

    // ---- phase 1: GEMM1a  kv[16][0:512] = M @ [Wk|Wv] (+bk,+bv)
    {
      v8bf amh[8], aml[8];
      #pragma unroll
      for (int kc = 0; kc < 8; ++kc) ldA_f32<15>(MfB, lane, kc, amh[kc], aml[kc]);
      for (int i = 0; i < 8; ++i){
        int nt = gwv * 8 + i;
        const v8bf* bph = ((const v8bf*)wbigh) + (nt*8)*64 + lane;
        const v8bf* bpl = ((const v8bf*)wbigl) + (nt*8)*64 + lane;
        v8bf bh[8], bl[8];
        #pragma unroll
        for (int kc = 0; kc < 8; ++kc){ bh[kc] = bph[kc*64]; bl[kc] = bpl[kc*64]; }
        v4f acc = {0.f, 0.f, 0.f, 0.f};
        #pragma unroll
        for (int kc = 0; kc < 8; ++kc) acc = MFMA16(amh[kc], bh[kc], acc);
        #pragma unroll
        for (int kc = 0; kc < 8; ++kc) acc = MFMA16(amh[kc], bl[kc], acc);
        #pragma unroll
        for (int kc = 0; kc < 8; ++kc) acc = MFMA16(aml[kc], bh[kc], acc);
        int n = nt*16 + (lane & 15);       // 0..511
        float bias = bkv[n];
        int r0 = (lane >> 4) * 4;
        #pragma unroll
        for (int r = 0; r < 4; ++r) kv[(r0 + r)*KVS + n] = acc[r] + bias;
      }
    }
    __syncthreads(); // b2

    // ---- phase 2: attention logits (16 slots x 16 threads per batch)
    {
      int s = bt >> 4;
      float p = 0.f;
      #pragma unroll
      for (int it = 0; it < 16; ++it){
        int j = (bt & 15) + it*16;
        p += xp[tt*1280 + j] * kv[s*KVS + j];
      }
      #pragma unroll
      for (int mm = 8; mm >= 1; mm >>= 1) p += __shfl_xor(p, mm);
      if ((bt & 15) == 0) scB[s] = p * 0.0625f;
    }
    __syncthreads(); // b3

    // ---- phase 3: softmax (redundant), r, pers momentum
    float nov;
    {
      float lg[16]; float mx = -1e30f;
      #pragma unroll
      for (int s2 = 0; s2 < 16; ++s2){ lg[s2] = scB[s2]; mx = fmaxf(mx, lg[s2]); }
      float at[16]; float ssum = 0.f;
      #pragma unroll
      for (int s2 = 0; s2 < 16; ++s2){ at[s2] = expf(lg[s2] - mx); ssum += at[s2]; }
      float inv = 1.0f / ssum;
      nov = 1.0f - inv;                    // max(attn) = 1/sum
      float rv = 0.f;
      #pragma unroll
      for (int s2 = 0; s2 < 16; ++s2) rv += (at[s2] * inv) * kv[s2*KVS + 256 + bt];
      rb[bt] = rv;
      if (bt < 16) scB[16 + bt] = 0.9f*scB[16 + bt] + 0.1f*(at[bt]*inv);
    }
    __syncthreads(); // b4

    // ---- phase 4: evict + GEMM2 (mv = r @ [wg1_r|fu_r]) + GEMM1b (eg|wc)
    if (bt < 16){
      float pv[16]; float mx = -1e30f;
      #pragma unroll
      for (int i = 0; i < 16; ++i){ pv[i] = -4.0f * scB[16 + i]; mx = fmaxf(mx, pv[i]); }
      float ev[16]; float ssum = 0.f;
      #pragma unroll
      for (int i = 0; i < 16; ++i){ ev[i] = expf(pv[i] - mx); ssum += ev[i]; }
      scB[32 + bt] = ev[bt] / ssum;
    }
    {
      v8bf arh[8], arl[8];
      #pragma unroll
      for (int kc = 0; kc < 8; ++kc) ldA_f32<0>(rbB, lane, kc, arh[kc], arl[kc]);
      for (int i = 0; i < 8; ++i){
        int nt = gwv * 8 + i;
        const v8bf* bph = ((const v8bf*)wrfh) + (nt*8)*64 + lane;
        v8bf bh[8];
        #pragma unroll
        for (int kc = 0; kc < 8; ++kc) bh[kc] = bph[kc*64];
        v4f acc = {0.f, 0.f, 0.f, 0.f};
        #pragma unroll
        for (int kc = 0; kc < 8; ++kc) acc = MFMA16(arh[kc], bh[kc], acc);
        #pragma unroll
        for (int kc = 0; kc < 8; ++kc) acc = MFMA16(arl[kc], bh[kc], acc);
        if (lane < 16) mvB[nt*16 + lane] = acc[0];   // C row 0
      }
    }
    {
      v8bf amh[8], aml[8];
      #pragma unroll
      for (int kc = 0; kc < 8; ++kc) ldA_f32<15>(MfB, lane, kc, amh[kc], aml[kc]);
      for (int i = 0; i < 8; ++i){
        int nt = 32 + gwv * 8 + i;
        const v8bf* bph = ((const v8bf*)wbigh) + (nt*8)*64 + lane;
        const v8bf* bpl = ((const v8bf*)wbigl) + (nt*8)*64 + lane;
        v8bf bh[8], bl[8];
        #pragma unroll
        for (int kc = 0; kc < 8; ++kc){ bh[kc] = bph[kc*64]; bl[kc] = bpl[kc*64]; }
        v4f acc = {0.f, 0.f, 0.f, 0.f};
        #pragma unroll
        for (int kc = 0; kc < 8; ++kc) acc = MFMA16(amh[kc], bh[kc], acc);
        #pragma unroll
        for (int kc = 0; kc < 8; ++kc) acc = MFMA16(amh[kc], bl[kc], acc);
        #pragma unroll
        for (int kc = 0; kc < 8; ++kc) acc = MFMA16(aml[kc], bh[kc], acc);
        int n = (nt - 32)*16 + (lane & 15);   // 0..511 : eg | wc
        int r0 = (lane >> 4) * 4;
        #pragma unroll
        for (int r = 0; r < 4; ++r) kv[(r0 + r)*KVS + n] = acc[r];
      }
    }
    __syncthreads(); // b5

    // ---- phase 5: gate-dot partials + fu gelu partials
    float gp = geluf(xp[tt*1280 + 256 + bt] + mvB[bt]) * wg2W[bt];
    float fpre = geluf(xp[tt*1280 + 1024 + bt] + mvB[256 + bt]);
    {
      float s1 = fpre, s2 = fpre*fpre;
      #pragma unroll
      for (int mm = 32; mm >= 1; mm >>= 1){
        gp += __shfl_xor(gp, mm);
        s1 += __shfl_xor(s1, mm); s2 += __shfl_xor(s2, mm);
      }
      if (lane == 0){
        scB[48 + gwv] = gp;
        scB[52 + 2*gwv] = s1; scB[53 + 2*gwv] = s2;
      }
    }
    __syncthreads(); // b6

    // ---- phase 6: gw, fu-LN, y, y partials, pers += evict*gw*0.1
    const float gw = sigmf(scB[48] + scB[49] + scB[50] + scB[51] + wg2b0) * nov;
    float y;
    {
      float fm = (scB[52] + scB[54] + scB[56] + scB[58]) * (1.0f/256.0f);
      float fq = (scB[53] + scB[55] + scB[57] + scB[59]) * (1.0f/256.0f);
      float o = (fpre - fm) * (1.0f / sqrtf(fq - fm*fm + 1e-5f)) * fug[bt] + fub[bt];
      float xv = *(const float*)(xbB + tt*1024 + ((bt*4) ^ (tt << 5)));
      y = o + xv;
      float s1 = y, s2 = y*y;
      #pragma unroll
      for (int mm = 32; mm >= 1; mm >>= 1){ s1 += __shfl_xor(s1, mm); s2 += __shfl_xor(s2, mm); }
      if (lane == 0){ scB[60 + 2*gwv] = s1; scB[61 + 2*gwv] = s2; }
      if (bt < 16) scB[16 + bt] += scB[32 + bt] * gw * 0.1f;
    }
    __syncthreads(); // b7

    // ---- phase 7: out write + M update (16 rows x 16 threads)
    {
      float m2 = (scB[60] + scB[62] + scB[64] + scB[66]) * (1.0f/256.0f);
      float q2 = (scB[61] + scB[63] + scB[65] + scB[67]) * (1.0f/256.0f);
      out[(size_t)t*NB*DD + (size_t)gb*DD + bt] =
          (y - m2) * (1.0f / sqrtf(q2 - m2*m2 + 1e-5f)) * ong[bt] + onb[bt];

      int s = bt >> 4;
      int l16 = bt & 15;
      float wp[16]; float s1 = 0.f, s2 = 0.f;
      #pragma unroll
      for (int jj = 0; jj < 16; ++jj){
        int n = l16 + jj*16;
        float wv = geluf(kv[s*KVS + 256 + n] + xp[tt*1280 + 768 + n]);
        wp[jj] = wv; s1 += wv; s2 += wv*wv;
      }
      #pragma unroll
      for (int mm = 8; mm >= 1; mm >>= 1){
        s1 += __shfl_xor(s1, mm); s2 += __shfl_xor(s2, mm);
      }
      float mean = s1 * (1.0f/256.0f);
      float rs = 1.0f / sqrtf(s2 * (1.0f/256.0f) - mean*mean + 1e-5f);
      float al = gw * scB[32 + s];
      #pragma unroll
      for (int jj = 0; jj < 16; ++jj){
        int n = l16 + jj*16;
        float er = sigmf(kv[s*KVS + n] + xp[tt*1280 + 512 + n]);
        float wn = (wp[jj] - mean)*rs*wcg[n] + wcb[n];
        float* mp = mfp(s, n);
        float m0 = *mp;
        *mp = m0*(1.0f - al*er) + al*wn;
      }
    }
    __syncthreads(); // b8
  }

  // ---- proto output: [K,B,d]
  {
    int s = bt >> 4;
    size_t base = (size_t)SLEN*NB*DD + ((size_t)s*NB + gb)*DD;
    #pragma unroll
    for (int jj = 0; jj < 16; ++jj){
      int n = (bt & 15) + jj*16;
      out[base + n] = *mfp(s, n);
    }
  }
}

extern "C" void kernel_launch(void* const* d_in, const int* in_sizes, int n_in,
                              void* d_out, int out_size, void* d_ws, size_t ws_size,
                              hipStream_t stream)
{
  const float* x     = (const float*)d_in[0];
  const float* si    = (const float*)d_in[1];
  const float* Wq    = (const float*)d_in[2];
  const float* bq    = (const float*)d_in[3];
  const float* Wk    = (const float*)d_in[4];
  const float* bk    = (const float*)d_in[5];
  const float* Wv    = (const float*)d_in[6];
  const float* bv    = (const float*)d_in[7];
  const float* wg1W  = (const float*)d_in[8];
  const float* wg1b  = (const float*)d_in[9];
  const float* wg2W  = (const float*)d_in[10];
  const float* wg2b  = (const float*)d_in[11];
  const float* egW   = (const float*)d_in[12];
  const float* egb   = (const float*)d_in[13];
  const float* wcW   = (const float*)d_in[14];
  const float* wcb   = (const float*)d_in[15];
  const float* wclng = (const float*)d_in[16];
  const float* wclnb = (const float*)d_in[17];
  const float* fuW   = (const float*)d_in[18];
  const float* fub   = (const float*)d_in[19];
  const float* fulng = (const float*)d_in[20];
  const float* fulnb = (const float*)d_in[21];
  const float* ong   = (const float*)d_in[22];
  const float* onb   = (const float*)d_in[23];
  float* out = (float*)d_out;

  char* ws = (char*)d_ws;
  uint16_t* wbigh = (uint16_t*)(ws);            // 512 KiB
  uint16_t* wbigl = (uint16_t*)(ws + 524288);   // 512 KiB
  uint16_t* wrfh  = (uint16_t*)(ws + 1048576);  // 256 KiB
  uint16_t* wxfh  = (uint16_t*)(ws + 1310720);  // 640 KiB
  uint16_t* wxfl  = (uint16_t*)(ws + 1966080);  // 640 KiB
  float* bxall    = (float*)(ws + 2621440);     // 5 KiB
  float* bkv      = (float*)(ws + 2626560);     // 2 KiB
  const size_t xpg_off = 2631680;               // 256B aligned
  float* Xpg      = (float*)(ws + xpg_off);     // 640 MiB if available
  const size_t need = xpg_off + (size_t)SLEN * NB * 1280 * 4;
  const int use_pre = (ws_size >= need) ? 1 : 0;

  hipLaunchKernelGGL(prep_kernel, dim3(2823), dim3(256), 0, stream,
                     Wq, Wk, Wv, wg1W, egW, wcW, fuW,
                     bq, wg1b, egb, wcb, fub, bk, bv,
                     wbigh, wbigl, wrfh, wxfh, wxfl, bxall, bkv);

  if (use_pre){
    hipLaunchKernelGGL(xproj_kernel, dim3(SLEN*NB/16), dim3(256), 0, stream,
                       x, wxfh, wxfl, bxall, Xpg);
  }

  hipFuncSetAttribute(reinterpret_cast<const void*>(memunit_kernel),
                      hipFuncAttributeMaxDynamicSharedMemorySize, SM_BYTES);
  hipLaunchKernelGGL(memunit_kernel, dim3(NB/2), dim3(TPB), SM_BYTES, stream,
                     x, si, wg2W, wg2b, wclng, wclnb, fulng, fulnb, ong, onb,
                     wbigh, wbigl, wrfh, wxfh, wxfl, bxall, bkv,
                     Xpg, use_pre, out);
}

// Round 5
// 141135.632 us; speedup vs baseline: 1.6128x; 1.6128x over previous
//
#include <hip/hip_runtime.h>
#include <stdint.h>
#include <stddef.h>

// MemoryUnit recurrent scan on MI355X (gfx950), round 5.
// 64 blocks x 512 threads, 1 batch/block (r3 structure, numerics identical).
// Key change vs r3: the weight-fragment stream is software-pipelined.
//  - __launch_bounds__(512,1): VGPR cap 512 (r3/r4 compiled at 128 VGPRs and
//    serialized every 16B fragment load at ~900cy; measured 190 loads x 880cy
//    == 70us/step exactly).
//  - GEMM1: 3 rotating register buffer-pairs, issue-ahead depth 3 (48 loads
//    in flight per wave), fully unrolled static indexing.
//  - GEMM2 B-fragments (wrf) persist in VGPRs across all 2048 steps.
//  - Xp (x-projections) precomputed into d_ws by xproj_kernel (pre-pass).
//  - kv LDS stride 1028 (2-way bank aliasing = free, vs 4-way at 1026).

#define SLEN 2048
#define NB   64
#define DD   256
#define TPB  512
#define KVSTR 1028

typedef __attribute__((ext_vector_type(8))) short v8bf;
typedef __attribute__((ext_vector_type(4))) float v4f;

__device__ __forceinline__ float bf2f(uint16_t h){
  union { uint32_t u; float f; } v; v.u = ((uint32_t)h) << 16; return v.f;
}
__device__ __forceinline__ uint16_t f2bf(float f){
  union { float f; uint32_t u; } v; v.f = f;
  uint32_t u = v.u;
  return (uint16_t)((u + 0x7FFFu + ((u >> 16) & 1u)) >> 16);
}
__device__ __forceinline__ void splitf(float f, uint16_t& h, uint16_t& l){
  h = f2bf(f);
  l = f2bf(f - bf2f(h));
}
__device__ __forceinline__ float geluf(float xx){
  return 0.5f * xx * (1.0f + erff(xx * 0.70710678118654752f));
}
__device__ __forceinline__ float sigmf(float xx){
  return 1.0f / (1.0f + expf(-xx));
}
__device__ __forceinline__ v4f MFMA16(v8bf a, v8bf b, v4f c){
  return __builtin_amdgcn_mfma_f32_16x16x32_bf16(a, b, c, 0, 0, 0);
}

// A-fragment load+split from fp32 LDS tile [R][256], row-swizzled:
// element (row,k) at byte row*1024 + ((k*4) ^ ((row&7)<<5)).
template<int RM>
__device__ __forceinline__ void ldA_f32(const char* base, int lane, int kc,
                                        v8bf& hi, v8bf& lo){
  int row = lane & RM;
  int off = row * 1024 + (((kc << 7) + ((lane >> 4) << 5)) ^ ((row & 7) << 5));
  const float* p = (const float*)(base + off);
  union { v8bf v; uint16_t u[8]; } H, L;
  #pragma unroll
  for (int j = 0; j < 8; ++j) splitf(p[j], H.u[j], L.u[j]);
  hi = H.v; lo = L.v;
}

// ---------------- weight packing ----------------
__global__ __launch_bounds__(256) void prep_kernel(
    const float* __restrict__ Wq, const float* __restrict__ Wk, const float* __restrict__ Wv,
    const float* __restrict__ wg1W, const float* __restrict__ egW, const float* __restrict__ wcW,
    const float* __restrict__ fuW,
    const float* __restrict__ bq, const float* __restrict__ bwg1, const float* __restrict__ beg,
    const float* __restrict__ bwc, const float* __restrict__ bfu,
    const float* __restrict__ bk, const float* __restrict__ bv,
    uint16_t* __restrict__ wbigh, uint16_t* __restrict__ wbigl,
    uint16_t* __restrict__ wrfh,
    uint16_t* __restrict__ wxfh, uint16_t* __restrict__ wxfl,
    float* __restrict__ bxall, float* __restrict__ bkv)
{
  int idx = blockIdx.x * 256 + threadIdx.x;
  if (idx < 262144){                               // Wbig: [Wk|Wv|egM|wcM] 256x1024
    int j = idx & 7, lane = (idx >> 3) & 63, kc = (idx >> 9) & 7, nt = idx >> 12;
    int k = kc*32 + ((lane >> 4) << 3) + j;
    int n = nt*16 + (lane & 15);
    float v;
    if (n < 256)      v = Wk[k*256 + n];
    else if (n < 512) v = Wv[k*256 + n - 256];
    else if (n < 768) v = egW[(256 + k)*256 + n - 512];
    else              v = wcW[(256 + k)*256 + n - 768];
    uint16_t h, l; splitf(v, h, l);
    wbigh[idx] = h; wbigl[idx] = l;
  }
  int i2 = idx - 262144;
  if (i2 >= 0 && i2 < 131072){                     // Wr: [wg1_r|fu_r] 256x512 (hi only)
    int j = i2 & 7, lane = (i2 >> 3) & 63, kc = (i2 >> 9) & 7, nt = i2 >> 12;
    int k = kc*32 + ((lane >> 4) << 3) + j;
    int n = nt*16 + (lane & 15);
    float v = (n < 256) ? wg1W[(256 + k)*256 + n] : fuW[(256 + k)*256 + n - 256];
    wrfh[i2] = f2bf(v);
  }
  int i3 = idx - 393216;
  if (i3 >= 0 && i3 < 327680){                     // Wx: [Wq|wg1_x|eg_x|wc_x|fu_x] 256x1280
    int j = i3 & 7, lane = (i3 >> 3) & 63, kc = (i3 >> 9) & 7, nt = i3 >> 12;
    int k = kc*32 + ((lane >> 4) << 3) + j;
    int n = nt*16 + (lane & 15);
    float v;
    if (n < 256)       v = Wq[k*256 + n];
    else if (n < 512)  v = wg1W[k*256 + n - 256];
    else if (n < 768)  v = egW[k*256 + n - 512];
    else if (n < 1024) v = wcW[k*256 + n - 768];
    else               v = fuW[k*256 + n - 1024];
    uint16_t h, l; splitf(v, h, l);
    wxfh[i3] = h; wxfl[i3] = l;
  }
  int i4 = idx - 720896;
  if (i4 >= 0 && i4 < 1280){
    float v;
    if (i4 < 256)       v = bq[i4];
    else if (i4 < 512)  v = bwg1[i4 - 256];
    else if (i4 < 768)  v = beg[i4 - 512];
    else if (i4 < 1024) v = bwc[i4 - 768];
    else                v = bfu[i4 - 1024];
    bxall[i4] = v;
  }
  int i5 = idx - 722176;
  if (i5 >= 0 && i5 < 512){
    bkv[i5] = (i5 < 256) ? bk[i5] : bv[i5 - 256];
  }
}

// ---------------- x-projection pre-pass ----------------
__global__ __launch_bounds__(256) void xproj_kernel(
    const float* __restrict__ x,
    const uint16_t* __restrict__ wxfh, const uint16_t* __restrict__ wxfl,
    const float* __restrict__ bxall, float* __restrict__ Xpg)
{
  __shared__ char xs[16384];                       // [16][256] f32 swizzled
  const int tid = threadIdx.x;
  const int lane = tid & 63;
  const int wv = tid >> 6;
  const int r0 = blockIdx.x * 16;
  {
    int row = tid >> 4;
    int c0 = (tid & 15) * 16;
    const float* xp = x + (size_t)(r0 + row) * 256 + c0;
    #pragma unroll
    for (int q = 0; q < 4; ++q){
      v4f v = *(const v4f*)(xp + q*4);
      int c = c0 + q*4;
      *(v4f*)(xs + row*1024 + ((c*4) ^ ((row & 7) << 5))) = v;
    }
  }
  __syncthreads();
  v8bf ah[8], al[8];
  #pragma unroll
  for (int kc = 0; kc < 8; ++kc) ldA_f32<15>(xs, lane, kc, ah[kc], al[kc]);
  for (int i = 0; i < 20; ++i){
    int nt = wv * 20 + i;
    const v8bf* bph = ((const v8bf*)wxfh) + (nt*8)*64 + lane;
    const v8bf* bpl = ((const v8bf*)wxfl) + (nt*8)*64 + lane;
    v8bf bh[8], bl[8];
    #pragma unroll
    for (int kc = 0; kc < 8; ++kc){ bh[kc] = bph[kc*64]; bl[kc] = bpl[kc*64]; }
    v4f acc = {0.f, 0.f, 0.f, 0.f};
    #pragma unroll
    for (int kc = 0; kc < 8; ++kc) acc = MFMA16(ah[kc], bh[kc], acc);
    #pragma unroll
    for (int kc = 0; kc < 8; ++kc) acc = MFMA16(ah[kc], bl[kc], acc);
    #pragma unroll
    for (int kc = 0; kc < 8; ++kc) acc = MFMA16(al[kc], bh[kc], acc);
    int n = nt*16 + (lane & 15);
    int rr = (lane >> 4) * 4;
    float bias = bxall[n];
    #pragma unroll
    for (int r = 0; r < 4; ++r)
      Xpg[(size_t)(r0 + rr + r) * 1280 + n] = acc[r] + bias;
  }
}

// ---------------- main persistent kernel ----------------
// LDS: MfB 0..16384 | xbB ..24576 | rbB ..25600 | kv ..91392 ([16][1028]f32)
//      Xp ..132352 ([8][1280]f32) | mv ..134400 | sc ..134672
#define SM_BYTES 134672

// GEMM1 pipeline macros: issue 16 loads for tile ii into named buffers, or
// consume (24 MFMA + biased store). Depth-3 rotation, fully unrolled.
#define G1_ISSUE(H, L, ii) \
  { const int off_ = ((wave*8 + (ii))*8)*64 + lane; \
    _Pragma("unroll") for (int kc = 0; kc < 8; ++kc){ \
      H[kc] = pbh_[off_ + kc*64]; L[kc] = pbl_[off_ + kc*64]; } }

#define G1_CONS(H, L, ii) \
  { v4f acc_ = {0.f,0.f,0.f,0.f}; \
    _Pragma("unroll") for (int kc = 0; kc < 8; ++kc) acc_ = MFMA16(amh[kc], H[kc], acc_); \
    _Pragma("unroll") for (int kc = 0; kc < 8; ++kc) acc_ = MFMA16(amh[kc], L[kc], acc_); \
    _Pragma("unroll") for (int kc = 0; kc < 8; ++kc) acc_ = MFMA16(aml[kc], H[kc], acc_); \
    const int n_ = (wave*8 + (ii))*16 + (lane & 15); \
    const float bias_ = (wave < 4) ? bkvR[(ii)] : 0.0f; \
    const int r0_ = (lane >> 4) << 2; \
    _Pragma("unroll") for (int r = 0; r < 4; ++r) kv[(r0_ + r)*KVSTR + n_] = acc_[r] + bias_; }

__global__ __launch_bounds__(TPB, 1) void memunit_kernel(
    const float* __restrict__ x, const float* __restrict__ slot_init,
    const float* __restrict__ wg2W, const float* __restrict__ wg2b,
    const float* __restrict__ wcg, const float* __restrict__ wcb,
    const float* __restrict__ fug, const float* __restrict__ fub,
    const float* __restrict__ ong, const float* __restrict__ onb,
    const uint16_t* __restrict__ wbigh, const uint16_t* __restrict__ wbigl,
    const uint16_t* __restrict__ wrfh,
    const uint16_t* __restrict__ wxfh, const uint16_t* __restrict__ wxfl,
    const float* __restrict__ bxall, const float* __restrict__ bkv,
    const float* __restrict__ Xpg, int use_pre,
    float* __restrict__ out)
{
  extern __shared__ char smem[];
  char*  MfB = smem;
  char*  xbB = smem + 16384;
  char*  rbB = smem + 24576;
  float* rb  = (float*)rbB;
  float* kv  = (float*)(smem + 25600);
  float* Xp  = (float*)(smem + 91392);
  float* mv  = (float*)(smem + 132352);
  float* sc  = (float*)(smem + 134400);
  // sc: [0..15] logits [16..31] pers [32..47] evict [48..51] gate partials
  //     [52..59] fu sum/sq [60..67] y sum/sq

  const int b    = blockIdx.x;
  const int tid  = threadIdx.x;
  const int lane = tid & 63;
  const int wave = tid >> 6;
  const int grp  = tid & 31;

  const float wg2b0 = wg2b[0];
  const v8bf* __restrict__ pbh_ = (const v8bf*)wbigh;
  const v8bf* __restrict__ pbl_ = (const v8bf*)wbigl;

  auto mfp = [&](int s, int n) -> float* {
    return (float*)(MfB + s*1024 + ((n*4) ^ ((s & 7) << 5)));
  };

  // ---- persistent per-wave state: GEMM2 B-fragments + GEMM1 biases
  v8bf wr[32];                                   // 128 VGPRs, live all steps
  {
    const v8bf* wp = ((const v8bf*)wrfh) + lane;
    #pragma unroll
    for (int i = 0; i < 4; ++i)
      #pragma unroll
      for (int kc = 0; kc < 8; ++kc)
        wr[i*8 + kc] = wp[((wave*4 + i)*8 + kc)*64];
  }
  float bkvR[8];
  #pragma unroll
  for (int i = 0; i < 8; ++i)
    bkvR[i] = (wave < 4) ? bkv[(wave*8 + i)*16 + (lane & 15)] : 0.0f;

  // ---- init: M from slot_init, rb zero, pers zero
  {
    int s = tid >> 5;
    int c0 = grp * 8;
    #pragma unroll
    for (int jj = 0; jj < 8; ++jj)
      *mfp(s, c0 + jj) = slot_init[s*256 + c0 + jj];
    if (tid < 256) rb[tid] = 0.0f;
    if (tid < 16)  sc[16 + tid] = 0.0f;
  }
  __syncthreads();

  for (int t = 0; t < SLEN; ++t){
    const int tt = t & 7;

    auto update_row = [&](int s, float gw_){
      float wp[8]; float s1 = 0.f, s2 = 0.f;
      #pragma unroll
      for (int jj = 0; jj < 8; ++jj){
        int n = grp + jj*32;
        float wv = geluf(kv[s*KVSTR + 768 + n] + Xp[tt*1280 + 768 + n]);
        wp[jj] = wv; s1 += wv; s2 += wv*wv;
      }
      #pragma unroll
      for (int mm = 16; mm >= 1; mm >>= 1){
        s1 += __shfl_xor(s1, mm); s2 += __shfl_xor(s2, mm);
      }
      float mean = s1 * (1.0f/256.0f);
      float rs = 1.0f / sqrtf(s2 * (1.0f/256.0f) - mean*mean + 1e-5f);
      float al = gw_ * sc[32 + s];
      #pragma unroll
      for (int jj = 0; jj < 8; ++jj){
        int n = grp + jj*32;
        float er = sigmf(kv[s*KVSTR + 512 + n] + Xp[tt*1280 + 512 + n]);
        float wn = (wp[jj] - mean)*rs*wcg[n] + wcb[n];
        float* mp = mfp(s, n);
        float m0 = *mp;
        *mp = m0*(1.0f - al*er) + al*wn;
      }
    };

    // ---- window start (every 8 steps): stage x chunk + Xp rows
    if (tt == 0){
      {
        int row = tid >> 6;
        int c0 = (tid & 63) * 4;
        v4f xv4 = *(const v4f*)(x + ((size_t)(t + row) * NB + b) * DD + c0);
        *(v4f*)(xbB + row*1024 + ((c0*4) ^ ((row & 7) << 5))) = xv4;
      }
      if (use_pre){
        int row = tid >> 6;
        int l6 = tid & 63;
        const float* src = Xpg + ((size_t)(t + row) * NB + b) * 1280;
        float* dst = Xp + row*1280;
        #pragma unroll
        for (int q = 0; q < 5; ++q){
          int c = (l6 + 64*q) * 4;
          *(v4f*)(dst + c) = *(const v4f*)(src + c);
        }
      } else {
        __syncthreads();
        v8bf ah[8], al8[8];
        #pragma unroll
        for (int kc = 0; kc < 8; ++kc) ldA_f32<7>(xbB, lane, kc, ah[kc], al8[kc]);
        for (int i = 0; i < 10; ++i){
          int nt = wave * 10 + i;
          const v8bf* bph = ((const v8bf*)wxfh) + (nt*8)*64 + lane;
          const v8bf* bpl = ((const v8bf*)wxfl) + (nt*8)*64 + lane;
          v8bf bh[8], bl[8];
          #pragma unroll
          for (int kc = 0; kc < 8; ++kc){ bh[kc] = bph[kc*64]; bl[kc] = bpl[kc*64]; }
          v4f acc = {0.f, 0.f, 0.f, 0.f};
          #pragma unroll
          for (int kc = 0; kc < 8; ++kc) acc = MFMA16(ah[kc], bh[kc], acc);
          #pragma unroll
          for (int kc = 0; kc < 8; ++kc) acc = MFMA16(ah[kc], bl[kc], acc);
          #pragma unroll
          for (int kc = 0; kc < 8; ++kc) acc = MFMA16(al8[kc], bh[kc], acc);
          int r0 = (lane >> 4) << 2;
          if (r0 < 8){
            int n = nt*16 + (lane & 15);
            float bias = bxall[n];
            #pragma unroll
            for (int r = 0; r < 4; ++r) Xp[(r0 + r)*1280 + n] = acc[r] + bias;
          }
        }
      }
    }

    // ---- phase 1: GEMM1  kv[16][1024] = M @ [Wk|Wv|egM|wcM] (+bk,+bv)
    // Software-pipelined: 3 rotating buffer-pairs, issue-ahead depth 3.
    {
      v8bf h0[8], l0[8], h1[8], l1[8], h2[8], l2[8];
      G1_ISSUE(h0, l0, 0)
      G1_ISSUE(h1, l1, 1)
      G1_ISSUE(h2, l2, 2)
      v8bf amh[8], aml[8];
      #pragma unroll
      for (int kc = 0; kc < 8; ++kc) ldA_f32<15>(MfB, lane, kc, amh[kc], aml[kc]);
      G1_CONS(h0, l0, 0)  G1_ISSUE(h0, l0, 3)
      G1_CONS(h1, l1, 1)  G1_ISSUE(h1, l1, 4)
      G1_CONS(h2, l2, 2)  G1_ISSUE(h2, l2, 5)
      G1_CONS(h0, l0, 3)  G1_ISSUE(h0, l0, 6)
      G1_CONS(h1, l1, 4)  G1_ISSUE(h1, l1, 7)
      G1_CONS(h2, l2, 5)
      G1_CONS(h0, l0, 6)
      G1_CONS(h1, l1, 7)
    }
    __syncthreads(); // b2

    // ---- phase 2: attention logits (16 slots x 32 threads)
    {
      int s = tid >> 5;
      float p = 0.f;
      #pragma unroll
      for (int it = 0; it < 8; ++it){
        int j = grp + it*32;
        p += Xp[tt*1280 + j] * kv[s*KVSTR + j];
      }
      #pragma unroll
      for (int mm = 16; mm >= 1; mm >>= 1) p += __shfl_xor(p, mm);
      if (grp == 0) sc[s] = p * 0.0625f;
    }
    __syncthreads(); // b3

    // ---- phase 3: softmax (redundant per-thread), r, pers momentum
    float nov;
    {
      float lg[16]; float mx = -1e30f;
      #pragma unroll
      for (int s2 = 0; s2 < 16; ++s2){ lg[s2] = sc[s2]; mx = fmaxf(mx, lg[s2]); }
      float at[16]; float ssum = 0.f;
      #pragma unroll
      for (int s2 = 0; s2 < 16; ++s2){ at[s2] = expf(lg[s2] - mx); ssum += at[s2]; }
      float inv = 1.0f / ssum;
      nov = 1.0f - inv;                      // max(attn) == 1/sum
      if (tid < 256){
        float rv = 0.f;
        #pragma unroll
        for (int s2 = 0; s2 < 16; ++s2) rv += (at[s2] * inv) * kv[s2*KVSTR + 256 + tid];
        rb[tid] = rv;
      }
      if (tid < 16) sc[16 + tid] = 0.9f*sc[16 + tid] + 0.1f*(at[tid]*inv);
    }
    __syncthreads(); // b4

    // ---- phase 4: evict (threads 0..15) + GEMM2 from persistent VGPRs
    if (tid < 16){
      float pv[16]; float mx = -1e30f;
      #pragma unroll
      for (int i = 0; i < 16; ++i){ pv[i] = -4.0f * sc[16 + i]; mx = fmaxf(mx, pv[i]); }
      float ev[16]; float ssum = 0.f;
      #pragma unroll
      for (int i = 0; i < 16; ++i){ ev[i] = expf(pv[i] - mx); ssum += ev[i]; }
      sc[32 + tid] = ev[tid] / ssum;
    }
    {
      v8bf arh[8], arl[8];
      #pragma unroll
      for (int kc = 0; kc < 8; ++kc) ldA_f32<0>(rbB, lane, kc, arh[kc], arl[kc]);
      #pragma unroll
      for (int i = 0; i < 4; ++i){
        v4f acc = {0.f, 0.f, 0.f, 0.f};
        #pragma unroll
        for (int kc = 0; kc < 8; ++kc) acc = MFMA16(arh[kc], wr[i*8 + kc], acc);
        #pragma unroll
        for (int kc = 0; kc < 8; ++kc) acc = MFMA16(arl[kc], wr[i*8 + kc], acc);
        if (lane < 16) mv[(wave*4 + i)*16 + lane] = acc[0];  // C row 0
      }
    }
    __syncthreads(); // b5

    // ---- phase 5: gate dot partials (tid<256) / fu gelu + LN partials
    float fpre = 0.f;
    if (tid < 256){
      float gp = geluf(Xp[tt*1280 + 256 + tid] + mv[tid]) * wg2W[tid];
      #pragma unroll
      for (int mm = 32; mm >= 1; mm >>= 1) gp += __shfl_xor(gp, mm);
      if (lane == 0) sc[48 + wave] = gp;
    } else {
      int j = tid - 256;
      fpre = geluf(Xp[tt*1280 + 1024 + j] + mv[256 + j]);
      float s1 = fpre, s2 = fpre*fpre;
      #pragma unroll
      for (int mm = 32; mm >= 1; mm >>= 1){ s1 += __shfl_xor(s1, mm); s2 += __shfl_xor(s2, mm); }
      if (lane == 0){ sc[52 + 2*(wave-4)] = s1; sc[52 + 2*(wave-4) + 1] = s2; }
    }
    __syncthreads(); // b6

    const float gw = sigmf(sc[48] + sc[49] + sc[50] + sc[51] + wg2b0) * nov;

    float y = 0.f;
    if (tid < 256){
      update_row(tid >> 5, gw);                       // M rows 0..7
      if (tid < 16) sc[16 + tid] += sc[32 + tid] * gw * 0.1f;
    } else {
      int j = tid - 256;
      float fm = (sc[52] + sc[54] + sc[56] + sc[58]) * (1.0f/256.0f);
      float fq = (sc[53] + sc[55] + sc[57] + sc[59]) * (1.0f/256.0f);
      float o = (fpre - fm) * (1.0f / sqrtf(fq - fm*fm + 1e-5f)) * fug[j] + fub[j];
      float xv = *(const float*)(xbB + tt*1024 + ((j*4) ^ ((tt & 7) << 5)));
      y = o + xv;
      float s1 = y, s2 = y*y;
      #pragma unroll
      for (int mm = 32; mm >= 1; mm >>= 1){ s1 += __shfl_xor(s1, mm); s2 += __shfl_xor(s2, mm); }
      if (lane == 0){ sc[60 + 2*(wave-4)] = s1; sc[60 + 2*(wave-4) + 1] = s2; }
    }
    __syncthreads(); // b7

    if (tid >= 256){
      int j = tid - 256;
      float m2 = (sc[60] + sc[62] + sc[64] + sc[66]) * (1.0f/256.0f);
      float q2 = (sc[61] + sc[63] + sc[65] + sc[67]) * (1.0f/256.0f);
      out[(size_t)t*NB*DD + (size_t)b*DD + j] =
          (y - m2) * (1.0f / sqrtf(q2 - m2*m2 + 1e-5f)) * ong[j] + onb[j];
      update_row(8 + ((tid - 256) >> 5), gw);         // M rows 8..15
    }
    __syncthreads(); // b8
  }

  // ---- proto output: [K,B,d]
  {
    int s = tid >> 5;
    size_t base = (size_t)SLEN*NB*DD + ((size_t)s*NB + b)*DD;
    #pragma unroll
    for (int jj = 0; jj < 8; ++jj){
      int n = grp + jj*32;
      out[base + n] = *mfp(s, n);
    }
  }
}

extern "C" void kernel_launch(void* const* d_in, const int* in_sizes, int n_in,
                              void* d_out, int out_size, void* d_ws, size_t ws_size,
                              hipStream_t stream)
{
  const float* x     = (const float*)d_in[0];
  const float* si    = (const float*)d_in[1];
  const float* Wq    = (const float*)d_in[2];
  const float* bq    = (const float*)d_in[3];
  const float* Wk    = (const float*)d_in[4];
  const float* bk    = (const float*)d_in[5];
  const float* Wv    = (const float*)d_in[6];
  const float* bv    = (const float*)d_in[7];
  const float* wg1W  = (const float*)d_in[8];
  const float* wg1b  = (const float*)d_in[9];
  const float* wg2W  = (const float*)d_in[10];
  const float* wg2b  = (const float*)d_in[11];
  const float* egW   = (const float*)d_in[12];
  const float* egb   = (const float*)d_in[13];
  const float* wcW   = (const float*)d_in[14];
  const float* wcb   = (const float*)d_in[15];
  const float* wclng = (const float*)d_in[16];
  const float* wclnb = (const float*)d_in[17];
  const float* fuW   = (const float*)d_in[18];
  const float* fub   = (const float*)d_in[19];
  const float* fulng = (const float*)d_in[20];
  const float* fulnb = (const float*)d_in[21];
  const float* ong   = (const float*)d_in[22];
  const float* onb   = (const float*)d_in[23];
  float* out = (float*)d_out;

  char* ws = (char*)d_ws;
  uint16_t* wbigh = (uint16_t*)(ws);            // 512 KiB
  uint16_t* wbigl = (uint16_t*)(ws + 524288);   // 512 KiB
  uint16_t* wrfh  = (uint16_t*)(ws + 1048576);  // 256 KiB
  uint16_t* wxfh  = (uint16_t*)(ws + 1310720);  // 640 KiB
  uint16_t* wxfl  = (uint16_t*)(ws + 1966080);  // 640 KiB
  float* bxall    = (float*)(ws + 2621440);     // 5 KiB
  float* bkv      = (float*)(ws + 2626560);     // 2 KiB
  const size_t xpg_off = 2631680;
  float* Xpg      = (float*)(ws + xpg_off);     // 640 MiB if available
  const size_t need = xpg_off + (size_t)SLEN * NB * 1280 * 4;
  const int use_pre = (ws_size >= need) ? 1 : 0;

  hipLaunchKernelGGL(prep_kernel, dim3(2823), dim3(256), 0, stream,
                     Wq, Wk, Wv, wg1W, egW, wcW, fuW,
                     bq, wg1b, egb, wcb, fub, bk, bv,
                     wbigh, wbigl, wrfh, wxfh, wxfl, bxall, bkv);

  if (use_pre){
    hipLaunchKernelGGL(xproj_kernel, dim3(SLEN*NB/16), dim3(256), 0, stream,
                       x, wxfh, wxfl, bxall, Xpg);
  }

  hipFuncSetAttribute(reinterpret_cast<const void*>(memunit_kernel),
                      hipFuncAttributeMaxDynamicSharedMemorySize, SM_BYTES);
  hipLaunchKernelGGL(memunit_kernel, dim3(NB), dim3(TPB), SM_BYTES, stream,
                     x, si, wg2W, wg2b, wclng, wclnb, fulng, fulnb, ong, onb,
                     wbigh, wbigl, wrfh, wxfh, wxfl, bxall, bkv,
                     Xpg, use_pre, out);
}